// Round 5
// baseline (381.919 us; speedup 1.0000x reference)
//
#include <hip/hip_runtime.h>
#include <hip/hip_bf16.h>

typedef unsigned int u32;
typedef unsigned short u16;
typedef u32 u32x2 __attribute__((ext_vector_type(2)));
typedef u32 u32x4v __attribute__((ext_vector_type(4)));
typedef short short8 __attribute__((ext_vector_type(8)));
typedef float f32x4 __attribute__((ext_vector_type(4)));

#define NGR 512     // graphs
#define NF 128      // edge features
#define GF 64       // global features
#define HID 64
#define IN1 192
#define NB 256      // one block per CU
#define TE 128      // edges per staged tile
#define EPB 6250    // E / NB (E = 1,600,000)
#define NTILES ((EPB + TE - 1) / TE)

__device__ __forceinline__ u16 f2bf(float x) {
    union { float f; u32 u; } a; a.f = x;
    u32 r = a.u + 0x7FFFu + ((a.u >> 16) & 1u);   // RNE
    return (u16)(r >> 16);
}

// LDS: transposed tile bufT[f(128)][c(128)] bf16, row stride 256B.
// Column permutation: c = pi(e) = (e&31)*4 + (e>>5)  (so each thread's 4
// staged edges land in 4 consecutive columns -> single ds_write_b64).
// Swizzle: byte_in_row ^= ((f&15)<<4)  -> conflict-free ds_read_b128 A-frags.
// MFMA k-slot (g4,j) <-> column ks*32+g4*8+j <-> segP[same index] (pre-permuted).

#define STAGE_LOAD(tile) do {                                                   \
    const int tb_ = (tile) * TE;                                                \
    _Pragma("unroll")                                                           \
    for (int p_ = 0; p_ < 4; ++p_) {                                            \
        const int el_ = tb_ + E0 + p_ * 32;                                     \
        f32x4 v_ = (f32x4){0.f, 0.f, 0.f, 0.f};                                 \
        if (el_ < EPB) v_ = *(const f32x4*)(edge_attr + (size_t)(estart + el_) * NF + qd * 4); \
        pv[p_] = v_;                                                            \
    }                                                                           \
    sv = 0xFFFF;                                                                \
    if (tid < TE) {                                                             \
        const int e_ = (tid >> 2) | ((tid & 3) << 5);   /* inverse perm */      \
        const int el_ = tb_ + e_;                                               \
        if (el_ < EPB) sv = batch[ei0[estart + el_]];                           \
    }                                                                           \
} while (0)

#define STAGE_WRITE(bi) do {                                                    \
    _Pragma("unroll")                                                           \
    for (int i_ = 0; i_ < 4; ++i_) {                                            \
        const int f_ = qd * 4 + i_;                                             \
        u32x2 w_;                                                               \
        w_.x = (u32)f2bf(pv[0][i_]) | ((u32)f2bf(pv[1][i_]) << 16);             \
        w_.y = (u32)f2bf(pv[2][i_]) | ((u32)f2bf(pv[3][i_]) << 16);             \
        *(u32x2*)((char*)(&bufT[bi][0]) + f_ * 256 + ((E0 * 8) ^ ((f_ & 15) << 4))) = w_; \
    }                                                                           \
    if (tid < TE) segP[bi][tid] = (u16)sv;                                      \
} while (0)

#define PROCESS(bi) do {                                                        \
    const char* base_ = (const char*)(&bufT[bi][0]);                            \
    const char* segb_ = (const char*)(&segP[bi][0]);                            \
    _Pragma("unroll 1")                                                         \
    for (int ks_ = 0; ks_ < 4; ++ks_) {                                         \
        u32x4v sw_ = *(const u32x4v*)(segb_ + ks_ * 64 + g4 * 16);              \
        int m0_, m1_, m2_, m3_, m4_, m5_, m6_, m7_;                             \
        { u32 lo_, hi_;                                                         \
          lo_ = sw_[0] & 0xFFFFu; hi_ = sw_[0] >> 16;                           \
          m0_ = ((int)(lo_ & 15u) == ln) ? (int)(lo_ >> 4) : -1;                \
          m1_ = ((int)(hi_ & 15u) == ln) ? (int)(hi_ >> 4) : -1;                \
          lo_ = sw_[1] & 0xFFFFu; hi_ = sw_[1] >> 16;                           \
          m2_ = ((int)(lo_ & 15u) == ln) ? (int)(lo_ >> 4) : -1;                \
          m3_ = ((int)(hi_ & 15u) == ln) ? (int)(hi_ >> 4) : -1;                \
          lo_ = sw_[2] & 0xFFFFu; hi_ = sw_[2] >> 16;                           \
          m4_ = ((int)(lo_ & 15u) == ln) ? (int)(lo_ >> 4) : -1;                \
          m5_ = ((int)(hi_ & 15u) == ln) ? (int)(hi_ >> 4) : -1;                \
          lo_ = sw_[3] & 0xFFFFu; hi_ = sw_[3] >> 16;                           \
          m6_ = ((int)(lo_ & 15u) == ln) ? (int)(lo_ >> 4) : -1;                \
          m7_ = ((int)(hi_ & 15u) == ln) ? (int)(hi_ >> 4) : -1; }              \
        union { u32x4v u; short8 s; } af0_, af1_, af2_, af3_;                   \
        { const int co_ = (ks_ * 64 + g4 * 16) ^ (ln << 4);                     \
          af0_.u = *(const u32x4v*)(base_ + ((wf4 + 0) * 16 + ln) * 256 + co_); \
          af1_.u = *(const u32x4v*)(base_ + ((wf4 + 1) * 16 + ln) * 256 + co_); \
          af2_.u = *(const u32x4v*)(base_ + ((wf4 + 2) * 16 + ln) * 256 + co_); \
          af3_.u = *(const u32x4v*)(base_ + ((wf4 + 3) * 16 + ln) * 256 + co_); } \
        _Pragma("unroll")                                                       \
        for (int gt_ = 0; gt_ < 4; ++gt_) {                                     \
            const int G_ = wg * 4 + gt_;                                        \
            union { u32x4v u; short8 s; } sf_;                                  \
            sf_.u[0] = (m0_ == G_ ? 0x3F80u : 0u) | (m1_ == G_ ? 0x3F800000u : 0u); \
            sf_.u[1] = (m2_ == G_ ? 0x3F80u : 0u) | (m3_ == G_ ? 0x3F800000u : 0u); \
            sf_.u[2] = (m4_ == G_ ? 0x3F80u : 0u) | (m5_ == G_ ? 0x3F800000u : 0u); \
            sf_.u[3] = (m6_ == G_ ? 0x3F80u : 0u) | (m7_ == G_ ? 0x3F800000u : 0u); \
            if (wf == 0) {                                                      \
                int c_ = (m0_ == G_) + (m1_ == G_) + (m2_ == G_) + (m3_ == G_)  \
                       + (m4_ == G_) + (m5_ == G_) + (m6_ == G_) + (m7_ == G_); \
                if (gt_ == 0) cnt0 += c_; else if (gt_ == 1) cnt1 += c_;        \
                else if (gt_ == 2) cnt2 += c_; else cnt3 += c_;                 \
            }                                                                   \
            acc[0][gt_] = __builtin_amdgcn_mfma_f32_16x16x32_bf16(af0_.s, sf_.s, acc[0][gt_], 0, 0, 0); \
            acc[1][gt_] = __builtin_amdgcn_mfma_f32_16x16x32_bf16(af1_.s, sf_.s, acc[1][gt_], 0, 0, 0); \
            acc[2][gt_] = __builtin_amdgcn_mfma_f32_16x16x32_bf16(af2_.s, sf_.s, acc[2][gt_], 0, 0, 0); \
            acc[3][gt_] = __builtin_amdgcn_mfma_f32_16x16x32_bf16(af3_.s, sf_.s, acc[3][gt_], 0, 0, 0); \
        }                                                                       \
    }                                                                           \
} while (0)

__launch_bounds__(1024, 4)
__global__ void stream_mfma_kernel(const float* __restrict__ edge_attr,
                                   const int* __restrict__ ei0,
                                   const int* __restrict__ batch,
                                   float* __restrict__ partial,
                                   float* __restrict__ cntp) {
    __shared__ __align__(16) u16 bufT[2][NF * TE];   // 2 x 32 KB, transposed
    __shared__ __align__(16) u16 segP[2][TE];        // permuted seg ids

    const int tid = threadIdx.x;
    const int b = blockIdx.x;
    const int wave = tid >> 6, lane = tid & 63;
    const int g4 = lane >> 4, ln = lane & 15;
    const int wf = wave >> 3, wg = wave & 7;         // 2 ft-groups x 8 gt-groups
    const int wf4 = wf * 4;
    const int estart = b * EPB;
    const int E0 = tid >> 5;    // column block (edge&31)
    const int qd = tid & 31;    // feat quad

    f32x4 acc[4][4];            // [ft 0..3][gt 0..3]
#pragma unroll
    for (int i = 0; i < 4; ++i)
#pragma unroll
        for (int j = 0; j < 4; ++j) acc[i][j] = (f32x4){0.f, 0.f, 0.f, 0.f};
    int cnt0 = 0, cnt1 = 0, cnt2 = 0, cnt3 = 0;

    f32x4 pv[4];
    int sv = 0xFFFF;

    STAGE_LOAD(0);
    STAGE_WRITE(0);
    __syncthreads();

#pragma unroll 1
    for (int t = 0; t < NTILES; ++t) {
        if (t + 1 < NTILES) STAGE_LOAD(t + 1);   // global->reg early (T14)
        PROCESS(t & 1);
        __syncthreads();
        if (t + 1 < NTILES) STAGE_WRITE((t + 1) & 1);
        __syncthreads();
    }

    // count reduce across the 4 lane-groups (each counted its own k-slots)
    cnt0 += __shfl_xor(cnt0, 16, 64); cnt0 += __shfl_xor(cnt0, 32, 64);
    cnt1 += __shfl_xor(cnt1, 16, 64); cnt1 += __shfl_xor(cnt1, 32, 64);
    cnt2 += __shfl_xor(cnt2, 16, 64); cnt2 += __shfl_xor(cnt2, 32, 64);
    cnt3 += __shfl_xor(cnt3, 16, 64); cnt3 += __shfl_xor(cnt3, 32, 64);
    if (wf == 0 && g4 == 0) {
        cntp[(size_t)b * NGR + (wg * 4 + 0) * 16 + ln] = (float)cnt0;
        cntp[(size_t)b * NGR + (wg * 4 + 1) * 16 + ln] = (float)cnt1;
        cntp[(size_t)b * NGR + (wg * 4 + 2) * 16 + ln] = (float)cnt2;
        cntp[(size_t)b * NGR + (wg * 4 + 3) * 16 + ln] = (float)cnt3;
    }

    // dump: C/D col=lane&15 -> graph-low, row=(lane>>4)*4+reg -> feat-low
#pragma unroll
    for (int ft = 0; ft < 4; ++ft)
#pragma unroll
        for (int gt = 0; gt < 4; ++gt) {
            const int graph = (wg * 4 + gt) * 16 + ln;
            const int fb = (wf4 + ft) * 16 + g4 * 4;
            *(f32x4*)(partial + ((size_t)b * NGR + graph) * NF + fb) = acc[ft][gt];
        }
}

__global__ void final_kernel(const float* __restrict__ partial,
                             const float* __restrict__ cntp,
                             const float* __restrict__ u,
                             const float* __restrict__ W1,
                             const float* __restrict__ b1,
                             const float* __restrict__ W2,
                             const float* __restrict__ b2,
                             float* __restrict__ out) {
    __shared__ float vin[IN1];
    __shared__ float hv[HID];
    __shared__ f32x4 red[8][32];
    __shared__ float csh[256];
    const int g = blockIdx.x, t = threadIdx.x;   // 256 threads

    csh[t] = cntp[(size_t)t * NGR + g];

    const int chunk = t & 31, grp = t >> 5;
    f32x4 s = {0.f, 0.f, 0.f, 0.f};
#pragma unroll 4
    for (int k = 0; k < 32; ++k) {
        int slab = grp + k * 8;
        const float4 vv = *(const float4*)(partial + ((size_t)slab * NGR + g) * NF + chunk * 4);
        s[0] += vv.x; s[1] += vv.y; s[2] += vv.z; s[3] += vv.w;
    }
    red[grp][chunk] = s;
    __syncthreads();
    if (t < 128) csh[t] += csh[t + 128];
    __syncthreads();
    if (t < 64) csh[t] += csh[t + 64];
    __syncthreads();
    if (t < 32) csh[t] += csh[t + 32];
    __syncthreads();
    if (t < 16) csh[t] += csh[t + 16];
    __syncthreads();
    if (t < 8) csh[t] += csh[t + 8];
    __syncthreads();
    if (t < 4) csh[t] += csh[t + 4];
    __syncthreads();
    if (t < 2) csh[t] += csh[t + 2];
    __syncthreads();
    if (t < 1) csh[t] += csh[t + 1];
    __syncthreads();
    const float cnt = fmaxf(csh[0], 1.0f);
    const float inv = 1.0f / cnt;
    if (t < GF) vin[t] = u[g * GF + t];
    if (t < 32) {
        f32x4 m = red[0][t];
#pragma unroll
        for (int r = 1; r < 8; ++r) {
            f32x4 q = red[r][t];
            m[0] += q[0]; m[1] += q[1]; m[2] += q[2]; m[3] += q[3];
        }
        vin[GF + t * 4 + 0] = m[0] * inv;
        vin[GF + t * 4 + 1] = m[1] * inv;
        vin[GF + t * 4 + 2] = m[2] * inv;
        vin[GF + t * 4 + 3] = m[3] * inv;
    }
    __syncthreads();
    if (t < HID) {
        float a = b1[t];
#pragma unroll
        for (int k = 0; k < IN1; ++k) a += vin[k] * W1[k * HID + t];
        hv[t] = fmaxf(a, 0.0f);
    }
    __syncthreads();
    if (t < GF) {
        float a = b2[t];
#pragma unroll
        for (int k = 0; k < HID; ++k) a += hv[k] * W2[k * GF + t];
        out[g * GF + t] = a;
    }
}

extern "C" void kernel_launch(void* const* d_in, const int* in_sizes, int n_in,
                              void* d_out, int out_size, void* d_ws, size_t ws_size,
                              hipStream_t stream) {
    // inputs: 0:x(unused) 1:edge_index[2,E] 2:edge_attr[E,128] 3:u[512,64]
    //         4:batch[50000] 5:W1[192,64] 6:b1[64] 7:W2[64,64] 8:b2[64]
    const int*   ei        = (const int*)d_in[1];
    const float* edge_attr = (const float*)d_in[2];
    const float* u         = (const float*)d_in[3];
    const int*   batch     = (const int*)d_in[4];
    const float* W1        = (const float*)d_in[5];
    const float* b1        = (const float*)d_in[6];
    const float* W2        = (const float*)d_in[7];
    const float* b2        = (const float*)d_in[8];
    float*       out       = (float*)d_out;

    const int* ei0 = ei;   // row 0 of edge_index

    // workspace: partial[NB][NGR][NF] f32 (64 MB) | cntp[NB][NGR] f32 (512 KB)
    float* partial = (float*)d_ws;
    float* cntp    = partial + (size_t)NB * NGR * NF;

    stream_mfma_kernel<<<NB, 1024, 0, stream>>>(edge_attr, ei0, batch, partial, cntp);
    final_kernel<<<NGR, 256, 0, stream>>>(partial, cntp, u, W1, b1, W2, b2, out);
}